// Round 8
// baseline (228.241 us; speedup 1.0000x reference)
//
#include <hip/hip_runtime.h>

#define NKEYS 64
#define UNROLL 8

typedef int   __attribute__((ext_vector_type(4))) i32x4;
typedef float __attribute__((ext_vector_type(4))) f32x4;

// out[i] = t[x[i]] where t is a 64-entry table derived from (keys, b):
//   t[v] = b[k] if keys[k] == (float)v for integral v in [0,64), else 0.
//
// v8: LOW-STREAM-COUNT round. All on-CU pipes are near-idle and policy is
//     settled (nt/nt best); kernel pinned at ~3.9 TB/s while the harness
//     fill does 6.7 TB/s at ~3 waves/CU and the m13 copy (same 50/50 R/W
//     mix) does 6.29 TB/s. Theory: 8192 concurrent wave-streams fragment
//     DRAM row locality; the fix is the fill's regime — few, long,
//     sequential streams. 512 blocks (2/CU), each walking one contiguous
//     256KB slice in 8x1KB unguarded batches (8KB/wave in flight covers
//     Little's law at 8 waves/CU).
__global__ __launch_bounds__(256) void sel_xform_kernel(
    const i32x4* __restrict__ in,
    const float* __restrict__ b,
    const float* __restrict__ keys,
    f32x4* __restrict__ out,
    int nvec, int slice, int ntail,
    const int* __restrict__ in_tail, float* __restrict__ out_tail)
{
    __shared__ float t[NKEYS];
    const int tid = threadIdx.x;
    if (tid < NKEYS) t[tid] = 0.0f;
    __syncthreads();
    if (tid < NKEYS) {
        const float kv = keys[tid];
        const int iv = (int)kv;
        if ((float)iv == kv && iv >= 0 && iv < NKEYS) {
            t[iv] = b[tid];   // keys are unique -> no write race
        }
    }
    __syncthreads();

    // Scalar tail (n % 4 elements), first few threads of block 0.
    if (blockIdx.x == 0 && tid < ntail) {
        const int v = in_tail[tid];
        out_tail[tid] = ((unsigned)v < NKEYS) ? t[v] : 0.0f;
    }

    // Branch-free table lookup: read t[v&63] (any LDS address in-bounds),
    // select 0 for out-of-range. 64-entry table = max 2-way bank aliasing,
    // which is free (m136).
    auto lut4 = [&](i32x4 v) -> f32x4 {
        const float rx = t[v.x & 63];
        const float ry = t[v.y & 63];
        const float rz = t[v.z & 63];
        const float rw = t[v.w & 63];
        f32x4 o;
        o.x = ((unsigned)v.x < NKEYS) ? rx : 0.0f;
        o.y = ((unsigned)v.y < NKEYS) ? ry : 0.0f;
        o.z = ((unsigned)v.z < NKEYS) ? rz : 0.0f;
        o.w = ((unsigned)v.w < NKEYS) ? rw : 0.0f;
        return o;
    };

    const int B = blockDim.x;          // 256
    const int batch = B * UNROLL;      // 2048 vec4 = 32KB per block-batch
    const int begin = blockIdx.x * slice;
    if (begin >= nvec) return;
    const int end = (begin + slice < nvec) ? (begin + slice) : nvec;

    int base = begin;
    // Full batches: 8 unguarded coalesced nt loads in flight, then 8 nt
    // stores. Block walks its slice strictly sequentially (one long stream).
    for (; base + batch <= end; base += batch) {
        i32x4 v[UNROLL];
#pragma unroll
        for (int j = 0; j < UNROLL; ++j)
            v[j] = __builtin_nontemporal_load(in + base + j * B + tid);
#pragma unroll
        for (int j = 0; j < UNROLL; ++j)
            __builtin_nontemporal_store(lut4(v[j]), out + base + j * B + tid);
    }
    // Ragged remainder (not hit for 8x4096x1024 with 512 blocks).
    for (; base < end; base += B) {
        const int i = base + tid;
        if (i < end) {
            const i32x4 v = __builtin_nontemporal_load(in + i);
            __builtin_nontemporal_store(lut4(v), out + i);
        }
    }
}

extern "C" void kernel_launch(void* const* d_in, const int* in_sizes, int n_in,
                              void* d_out, int out_size, void* d_ws, size_t ws_size,
                              hipStream_t stream) {
    const int*   x    = (const int*)d_in[0];     // inputs, int32, [8,4096,1024]
    const float* b    = (const float*)d_in[1];   // per-key bias, [64]
    const float* keys = (const float*)d_in[2];   // sorted unique keys, [64]
    float* out = (float*)d_out;

    const int n    = in_sizes[0];
    const int nvec = n >> 2;        // int4 / float4 groups
    const int ntail = n & 3;

    const int block = 256;
    const int batch = block * UNROLL;            // 2048 vec4 per batch

    // 512 contiguous slices (2 blocks/CU): few long sequential streams.
    int grid = 512;
    int maxg = (nvec + batch - 1) / batch;
    if (grid > maxg) grid = maxg;
    if (grid < 1) grid = 1;
    int slice = (nvec + grid - 1) / grid;
    slice = ((slice + batch - 1) / batch) * batch;   // whole batches per slice
    grid = (nvec + slice - 1) / slice;               // shrink if over-covered

    sel_xform_kernel<<<grid, block, 0, stream>>>(
        (const i32x4*)x, b, keys, (f32x4*)out,
        nvec, slice, ntail, x + (nvec << 2), out + (nvec << 2));
}

// Round 9
// 225.153 us; speedup vs baseline: 1.0137x; 1.0137x over previous
//
#include <hip/hip_runtime.h>

#define NKEYS 64

typedef int   __attribute__((ext_vector_type(4))) i32x4;
typedef float __attribute__((ext_vector_type(4))) f32x4;

// out[i] = t[x[i]] where t is a 64-entry table derived from (keys, b):
//   t[v] = b[k] if keys[k] == (float)v for integral v in [0,64), else 0.
//
// v9: r0's proven shape (full grid, ONE vec4 per thread, no loop) + nt on
//     both sides. Evidence: r0 (full grid, wb/wb) beat 2048-grid/UNROLL=4
//     (wb/wb) by ~8us — one-tile-per-block gives the tightest device-level
//     sequential sweep and block retire/launch naturally overlaps read and
//     write phases across blocks (hardware pipelining; the software version
//     in r7 regressed). nt loads are worth ~11us independently (r4->r6).
//     Contiguous-slice partitioning falsified (r7/r8 both ~+6us).
__global__ __launch_bounds__(256) void sel_xform_kernel(
    const i32x4* __restrict__ in,
    const float* __restrict__ b,
    const float* __restrict__ keys,
    f32x4* __restrict__ out,
    int nvec, int ntail, const int* __restrict__ in_tail, float* __restrict__ out_tail)
{
    __shared__ float t[NKEYS];
    const int tid = threadIdx.x;
    if (tid < NKEYS) t[tid] = 0.0f;
    __syncthreads();
    if (tid < NKEYS) {
        const float kv = keys[tid];
        const int iv = (int)kv;
        if ((float)iv == kv && iv >= 0 && iv < NKEYS) {
            t[iv] = b[tid];   // keys are unique -> no write race
        }
    }
    __syncthreads();

    // Branch-free table lookup: read t[v&63] (any LDS address is in-bounds),
    // then select 0 for out-of-range values. 64-entry table spans 2 rows of
    // the 32 banks -> worst case 2-way aliasing, which is free (m136).
    auto lut4 = [&](i32x4 v) -> f32x4 {
        const float rx = t[v.x & 63];
        const float ry = t[v.y & 63];
        const float rz = t[v.z & 63];
        const float rw = t[v.w & 63];
        f32x4 o;
        o.x = ((unsigned)v.x < NKEYS) ? rx : 0.0f;
        o.y = ((unsigned)v.y < NKEYS) ? ry : 0.0f;
        o.z = ((unsigned)v.z < NKEYS) ? rz : 0.0f;
        o.w = ((unsigned)v.w < NKEYS) ? rw : 0.0f;
        return o;
    };

    // One vec4 per thread; grid covers nvec exactly (loop kept for safety,
    // executes once at this problem size).
    int i = blockIdx.x * blockDim.x + tid;
    const int stride = gridDim.x * blockDim.x;
    for (; i < nvec; i += stride) {
        const i32x4 v = __builtin_nontemporal_load(in + i);
        __builtin_nontemporal_store(lut4(v), out + i);
    }

    // Scalar tail (n % 4 elements), handled by the first few threads of block 0.
    if (blockIdx.x == 0 && tid < ntail) {
        const int v = in_tail[tid];
        out_tail[tid] = ((unsigned)v < NKEYS) ? t[v] : 0.0f;
    }
}

extern "C" void kernel_launch(void* const* d_in, const int* in_sizes, int n_in,
                              void* d_out, int out_size, void* d_ws, size_t ws_size,
                              hipStream_t stream) {
    const int*   x    = (const int*)d_in[0];     // inputs, int32, [8,4096,1024]
    const float* b    = (const float*)d_in[1];   // per-key bias, [64]
    const float* keys = (const float*)d_in[2];   // sorted unique keys, [64]
    float* out = (float*)d_out;

    const int n    = in_sizes[0];
    const int nvec = n >> 2;        // int4 / float4 groups
    const int ntail = n & 3;

    const int block = 256;
    // Full grid: one 4KB-read tile per block (32768 blocks at this size).
    int grid = (nvec + block - 1) / block;
    if (grid < 1) grid = 1;

    sel_xform_kernel<<<grid, block, 0, stream>>>(
        (const i32x4*)x, b, keys, (f32x4*)out,
        nvec, ntail, x + (nvec << 2), out + (nvec << 2));
}

// Round 10
// 222.379 us; speedup vs baseline: 1.0264x; 1.0125x over previous
//
#include <hip/hip_runtime.h>

#define NKEYS 64
#define UNROLL 4

typedef int   __attribute__((ext_vector_type(4))) i32x4;
typedef float __attribute__((ext_vector_type(4))) f32x4;

// out[i] = t[x[i]] where t is a 64-entry table derived from (keys, b):
//   t[v] = b[k] if keys[k] == (float)v for integral v in [0,64), else 0.
//
// v10 = v5 (REVERT TO BEST): nt loads + nt stores, direct LDS lookup,
//     4x unrolled block-uniform fast path, 2048-block grid-stride (exactly
//     4 passes). Best measured config: bench 221.5us, kernel ~68.5us.
//     Full config-space result (10 rounds): policy 2x2 complete (nt/nt best,
//     -11us vs wb load; store policy neutral), unroll {1,4,8}, partitioning
//     {grid-stride, contiguous-slice, one-tile-per-block} (grid-stride best),
//     occupancy {512, 2048, 32768 blocks}, software pipelining (regressed).
//     All variants land in a 68-80us kernel band with on-CU pipes idle;
//     remaining gap to the 43us copy roofline is the memory system's
//     mixed-stream rate with an L3-straddling 256MiB working set.
__global__ __launch_bounds__(256) void sel_xform_kernel(
    const i32x4* __restrict__ in,
    const float* __restrict__ b,
    const float* __restrict__ keys,
    f32x4* __restrict__ out,
    int nvec, int ntail, const int* __restrict__ in_tail, float* __restrict__ out_tail)
{
    __shared__ float t[NKEYS];
    const int tid = threadIdx.x;
    if (tid < NKEYS) t[tid] = 0.0f;
    __syncthreads();
    if (tid < NKEYS) {
        const float kv = keys[tid];
        const int iv = (int)kv;
        if ((float)iv == kv && iv >= 0 && iv < NKEYS) {
            t[iv] = b[tid];   // keys are unique -> no write race
        }
    }
    __syncthreads();

    const int B = blockDim.x;                 // 256
    const int chunk = gridDim.x * B * UNROLL; // elements per grid pass

    // Branch-free table lookup: read t[v&63] (any LDS address is in-bounds),
    // then select 0 for out-of-range values. 64-entry table spans 2 rows of
    // the 32 banks -> worst case 2-way aliasing, which is free (m136).
    auto lut4 = [&](i32x4 v) -> f32x4 {
        const float rx = t[v.x & 63];
        const float ry = t[v.y & 63];
        const float rz = t[v.z & 63];
        const float rw = t[v.w & 63];
        f32x4 o;
        o.x = ((unsigned)v.x < NKEYS) ? rx : 0.0f;
        o.y = ((unsigned)v.y < NKEYS) ? ry : 0.0f;
        o.z = ((unsigned)v.z < NKEYS) ? rz : 0.0f;
        o.w = ((unsigned)v.w < NKEYS) ? rw : 0.0f;
        return o;
    };

    for (int base = blockIdx.x * B * UNROLL; base < nvec; base += chunk) {
        if (base + UNROLL * B <= nvec) {
            // Fast path (block-uniform condition, no divergence): 4 coalesced
            // streaming loads in flight per wave, then 4 streaming stores.
            const int i0 = base + tid;
            const i32x4 v0 = __builtin_nontemporal_load(in + i0);
            const i32x4 v1 = __builtin_nontemporal_load(in + i0 + B);
            const i32x4 v2 = __builtin_nontemporal_load(in + i0 + 2 * B);
            const i32x4 v3 = __builtin_nontemporal_load(in + i0 + 3 * B);

            __builtin_nontemporal_store(lut4(v0), out + i0);
            __builtin_nontemporal_store(lut4(v1), out + i0 + B);
            __builtin_nontemporal_store(lut4(v2), out + i0 + 2 * B);
            __builtin_nontemporal_store(lut4(v3), out + i0 + 3 * B);
        } else {
            // Ragged last chunk: per-element guards (not hit for 8x4096x1024).
            for (int j = 0; j < UNROLL; ++j) {
                const int i = base + j * B + tid;
                if (i < nvec) {
                    const i32x4 v = __builtin_nontemporal_load(in + i);
                    __builtin_nontemporal_store(lut4(v), out + i);
                }
            }
        }
    }

    // Scalar tail (n % 4 elements), handled by the first few threads of block 0.
    if (blockIdx.x == 0 && tid < ntail) {
        const int v = in_tail[tid];
        out_tail[tid] = ((unsigned)v < NKEYS) ? t[v] : 0.0f;
    }
}

extern "C" void kernel_launch(void* const* d_in, const int* in_sizes, int n_in,
                              void* d_out, int out_size, void* d_ws, size_t ws_size,
                              hipStream_t stream) {
    const int*   x    = (const int*)d_in[0];     // inputs, int32, [8,4096,1024]
    const float* b    = (const float*)d_in[1];   // per-key bias, [64]
    const float* keys = (const float*)d_in[2];   // sorted unique keys, [64]
    float* out = (float*)d_out;

    const int n    = in_sizes[0];
    const int nvec = n >> 2;        // int4 / float4 groups
    const int ntail = n & 3;

    const int block = 256;
    // 2048 blocks = 8 blocks/CU; with UNROLL=4 the 8.39M vec4 are covered in
    // exactly 4 grid passes with no ragged iterations.
    int grid = (nvec + block * UNROLL - 1) / (block * UNROLL);
    if (grid > 2048) grid = 2048;
    if (grid < 1) grid = 1;

    sel_xform_kernel<<<grid, block, 0, stream>>>(
        (const i32x4*)x, b, keys, (f32x4*)out,
        nvec, ntail, x + (nvec << 2), out + (nvec << 2));
}